// Round 1
// baseline (53.383 us; speedup 1.0000x reference)
//
#include <hip/hip_runtime.h>

#define HH 40
#define WW 40
#define NP 36
#define NC 256
#define NB 128

// Kernel 1: per-batch offset GEMM + point computation.
// block = 128 threads, grid = 128 (one block per batch).
__global__ void points_kernel(const float* __restrict__ cq,
                              const float* __restrict__ refp,
                              const float* __restrict__ Woff,
                              const float* __restrict__ boff,
                              float2* __restrict__ pts) {
    int b = blockIdx.x;
    __shared__ float q[NC];
    __shared__ float offs[2 * NP];
    for (int i = threadIdx.x; i < NC; i += blockDim.x) q[i] = cq[b * NC + i];
    __syncthreads();
    int j = threadIdx.x;
    if (j < 2 * NP) {
        const float* w = Woff + j * NC;
        float acc = 0.f;
#pragma unroll 8
        for (int k = 0; k < NC; ++k) acc = fmaf(q[k], w[k], acc);
        offs[j] = acc + boff[j];
    }
    __syncthreads();
    int p = threadIdx.x;
    if (p < NP) {
        float sx = offs[2 * p + 0] + refp[b * 2 + 0];
        float sy = offs[2 * p + 1] + refp[b * 2 + 1];
        // grid = 2*s - 1 ; pix = ((g+1)*size - 1)/2 = s*size - 0.5 ; border clamp
        float x = fminf(fmaxf(sx * (float)WW - 0.5f, 0.f), (float)(WW - 1));
        float y = fminf(fmaxf(sy * (float)HH - 0.5f, 0.f), (float)(HH - 1));
        pts[b * NP + p] = make_float2(x, y);
    }
}

// Kernel 2: bilinear gather for both maps. One thread per (b,c,p).
// p varies fastest -> a wave's first 36 lanes share one (b,c) image: L1 reuse.
__global__ void sample_kernel(const float* __restrict__ fmap,
                              const float* __restrict__ pmap,
                              const float2* __restrict__ pts,
                              float* __restrict__ out) {
    long tid = (long)blockIdx.x * blockDim.x + threadIdx.x;
    const long total = (long)NB * NC * NP;
    if (tid >= total) return;
    int p = (int)(tid % NP);
    long t2 = tid / NP;
    int c = (int)(t2 % NC);
    int b = (int)(t2 / NC);

    float2 xy = pts[b * NP + p];
    float x0f = floorf(xy.x), y0f = floorf(xy.y);
    float wx = xy.x - x0f, wy = xy.y - y0f;
    int x0 = (int)x0f, y0 = (int)y0f;
    int x1 = min(x0 + 1, WW - 1), y1 = min(y0 + 1, HH - 1);

    long base = ((long)b * NC + c) * (HH * WW);
    int i00 = y0 * WW + x0;
    int i01 = y0 * WW + x1;
    int i10 = y1 * WW + x0;
    int i11 = y1 * WW + x1;

    float w00 = (1.f - wx) * (1.f - wy);
    float w01 = wx * (1.f - wy);
    float w10 = (1.f - wx) * wy;
    float w11 = wx * wy;

    float f = fmap[base + i00] * w00 + fmap[base + i01] * w01 +
              fmap[base + i10] * w10 + fmap[base + i11] * w11;
    float g = pmap[base + i00] * w00 + pmap[base + i01] * w01 +
              pmap[base + i10] * w10 + pmap[base + i11] * w11;

    long oidx = ((long)b * NC + c) * NP + p;
    out[oidx] = f;
    out[(long)NB * NC * NP + oidx] = g;
}

extern "C" void kernel_launch(void* const* d_in, const int* in_sizes, int n_in,
                              void* d_out, int out_size, void* d_ws, size_t ws_size,
                              hipStream_t stream) {
    const float* cq   = (const float*)d_in[0];  // (128, 256)
    const float* refp = (const float*)d_in[1];  // (128, 2)
    const float* fmap = (const float*)d_in[2];  // (128, 256, 1600)
    const float* pmap = (const float*)d_in[3];  // (128, 256, 1600)
    const float* Woff = (const float*)d_in[4];  // (72, 256)
    const float* boff = (const float*)d_in[5];  // (72,)
    float* out = (float*)d_out;
    float2* pts = (float2*)d_ws;  // 128*36 float2 = 36,864 B

    points_kernel<<<NB, 128, 0, stream>>>(cq, refp, Woff, boff, pts);

    const long total = (long)NB * NC * NP;  // 1,179,648
    int block = 256;
    int grid = (int)((total + block - 1) / block);  // 4608
    sample_kernel<<<grid, block, 0, stream>>>(fmap, pmap, pts, out);
}